// Round 3
// baseline (340.287 us; speedup 1.0000x reference)
//
#include <hip/hip_runtime.h>

#define B_ROWS 8192
#define IN_F 512
#define OUT_F 1024
#define K_TOT 1536

#define BM 128
#define BN 128
#define BK 64
#define NITER (K_TOT / BK)          // 24

#define A4_COUNT (B_ROWS * (K_TOT / 4))   // 3,145,728 float4s
#define W4_COUNT (OUT_F  * (K_TOT / 4))   //   393,216 float4s

typedef short bfrag __attribute__((ext_vector_type(8)));   // 8 bf16 = 4 VGPRs
typedef float f4    __attribute__((ext_vector_type(4)));

typedef __attribute__((address_space(3))) unsigned short lds_us;
typedef __attribute__((address_space(1))) const unsigned short gbl_us;

// round-to-nearest-even fp32 -> bf16, packed pairwise into a dword
__device__ __forceinline__ unsigned int pack2bf(float a, float b) {
    unsigned int ua = __float_as_uint(a);
    unsigned int ub = __float_as_uint(b);
    ua = (ua + 0x7fffu + ((ua >> 16) & 1u)) >> 16;
    ub = (ub + 0x7fffu + ((ub >> 16) & 1u)) & 0xffff0000u;
    return ua | ub;
}

// ---------------- pass 1: fp32 -> bf16 precast into packed A/W -------------
// A_bf16[8192][1536] = [spikes | z], W_bf16[1024][1536] = [Wi | Wr]
__global__ __launch_bounds__(256) void precast(
    const float* __restrict__ spikes, const float* __restrict__ zin,
    const float* __restrict__ Wi,     const float* __restrict__ Wr,
    unsigned short* __restrict__ Abf, unsigned short* __restrict__ Wbf)
{
    const int idx = blockIdx.x * 256 + threadIdx.x;   // float4 index
    const float* src;
    unsigned short* dst;
    if (idx < A4_COUNT) {
        const int row = idx / 384, c4 = idx - row * 384;
        src = (c4 < 128) ? spikes + (size_t)row * IN_F + c4 * 4
                         : zin    + (size_t)row * OUT_F + (c4 - 128) * 4;
        dst = Abf + (size_t)idx * 4;
    } else {
        const int w = idx - A4_COUNT;
        const int row = w / 384, c4 = w - row * 384;
        src = (c4 < 128) ? Wi + (size_t)row * IN_F + c4 * 4
                         : Wr + (size_t)row * OUT_F + (c4 - 128) * 4;
        dst = Wbf + (size_t)w * 4;
    }
    const float4 v = *(const float4*)src;
    uint2 pk = { pack2bf(v.x, v.y), pack2bf(v.z, v.w) };
    *(uint2*)dst = pk;
}

// ---------------- pass 2: bf16 GEMM (m97 structure) + fused LSNN -----------
__global__ __launch_bounds__(256, 2) void lsnn_gemm(
    const unsigned short* __restrict__ Abf,   // [8192, 1536] bf16
    const unsigned short* __restrict__ Wbf,   // [1024, 1536] bf16
    const float* __restrict__ vin,
    const float* __restrict__ iin,
    const float* __restrict__ bin,
    float* __restrict__ out)                  // [4, B, 1024]
{
    __shared__ unsigned short As[BM * BK];    // 16 KB (no pad: global_load_lds layout)
    __shared__ unsigned short Ws[BN * BK];    // 16 KB

    const int tid = threadIdx.x;
    const int bid = blockIdx.x;
    const int n0 = (bid & 7) * BN;   // blocks round-robin XCDs -> W slice pinned per XCD L2
    const int m0 = (bid >> 3) * BM;

    const int lane = tid & 63;
    const int wave = tid >> 6;
    const int wm = (wave >> 1) * 64;
    const int wn = (wave & 1) * 64;
    const int lr = lane & 15;
    const int lq = lane >> 4;

    f4 acc[4][4];
    #pragma unroll
    for (int a = 0; a < 4; ++a)
        #pragma unroll
        for (int b = 0; b < 4; ++b)
            acc[a][b] = (f4)0.0f;

    const unsigned short* Ab = Abf + (size_t)m0 * K_TOT;
    const unsigned short* Wb = Wbf + (size_t)n0 * K_TOT;

    for (int it = 0; it < NITER; ++it) {
        const int kt = it * BK;
        __syncthreads();   // previous iteration's ds_reads done before overwrite

        // HBM -> LDS direct, 16 B/lane. Tile = 128 rows x 128 B, stored row-major
        // contiguous in LDS. chunk j (16 B): row = j>>3, col16 = j&7.
        // Wave covers 64 consecutive chunks; LDS dst = wave-uniform base + lane*16.
        #pragma unroll
        for (int p = 0; p < 4; ++p) {
            const int j0 = p * 256 + wave * 64;
            const int j  = j0 + lane;
            const int row = j >> 3, c16 = j & 7;
            __builtin_amdgcn_global_load_lds(
                (const __attribute__((address_space(1))) void*)(Ab + (size_t)row * K_TOT + kt + c16 * 8),
                (__attribute__((address_space(3))) void*)(As + j0 * 8),
                16, 0, 0);
        }
        #pragma unroll
        for (int p = 0; p < 4; ++p) {
            const int j0 = p * 256 + wave * 64;
            const int j  = j0 + lane;
            const int row = j >> 3, c16 = j & 7;
            __builtin_amdgcn_global_load_lds(
                (const __attribute__((address_space(1))) void*)(Wb + (size_t)row * K_TOT + kt + c16 * 8),
                (__attribute__((address_space(3))) void*)(Ws + j0 * 8),
                16, 0, 0);
        }
        __syncthreads();   // compiler drains vmcnt before s_barrier

        #pragma unroll
        for (int ks = 0; ks < 2; ++ks) {
            const int kk = ks * 32 + lq * 8;
            bfrag af[4], wf[4];
            #pragma unroll
            for (int t = 0; t < 4; ++t) {
                af[t] = *(const bfrag*)&As[(wm + t * 16 + lr) * BK + kk];
                wf[t] = *(const bfrag*)&Ws[(wn + t * 16 + lr) * BK + kk];
            }
            #pragma unroll
            for (int tm = 0; tm < 4; ++tm)
                #pragma unroll
                for (int tn = 0; tn < 4; ++tn)
                    acc[tm][tn] = __builtin_amdgcn_mfma_f32_16x16x32_bf16(
                        af[tm], wf[tn], acc[tm][tn], 0, 0, 0);
        }
    }

    // Epilogue: C/D mapping col = lane&15, row = (lane>>4)*4 + reg (m89/m91)
    const size_t PL = (size_t)B_ROWS * OUT_F;
    #pragma unroll
    for (int tm = 0; tm < 4; ++tm) {
        #pragma unroll
        for (int tn = 0; tn < 4; ++tn) {
            #pragma unroll
            for (int r = 0; r < 4; ++r) {
                const int gm = m0 + wm + tm * 16 + lq * 4 + r;
                const int gn = n0 + wn + tn * 16 + lr;
                const size_t idx = (size_t)gm * OUT_F + gn;
                const float v = vin[idx];
                const float i = iin[idx];
                const float b = bin[idx];
                const float v_dec = v + 0.1f * ((0.0f - v) + i);   // dt*tau_mem_inv
                const float i_dec = i - 0.2f * i;                  // dt*tau_syn_inv
                const float b_dec = b + 1.25e-06f * (1.0f - b);    // dt*tau_adapt_inv
                const float zn = (v_dec - b_dec > 0.0f) ? 1.0f : 0.0f;
                const float vn = (1.0f - zn) * v_dec;              // v_reset = 0
                const float inew = i_dec + acc[tm][tn][r];
                const float bnew = b_dec + zn * 0.00225f;          // tau_adapt_inv*beta
                out[idx]          = zn;
                out[PL + idx]     = vn;
                out[2 * PL + idx] = inew;
                out[3 * PL + idx] = bnew;
            }
        }
    }
}

extern "C" void kernel_launch(void* const* d_in, const int* in_sizes, int n_in,
                              void* d_out, int out_size, void* d_ws, size_t ws_size,
                              hipStream_t stream) {
    const float* spikes = (const float*)d_in[0];
    const float* z      = (const float*)d_in[1];
    const float* v      = (const float*)d_in[2];
    const float* i      = (const float*)d_in[3];
    const float* b      = (const float*)d_in[4];
    const float* Wi     = (const float*)d_in[5];
    const float* Wr     = (const float*)d_in[6];
    float* out = (float*)d_out;

    unsigned short* Abf = (unsigned short*)d_ws;                       // 25,165,824 B
    unsigned short* Wbf = Abf + (size_t)B_ROWS * K_TOT;                //  3,145,728 B

    const int pc_grid = (A4_COUNT + W4_COUNT) / 256;                   // 13824
    precast<<<pc_grid, 256, 0, stream>>>(spikes, z, Wi, Wr, Abf, Wbf);

    const int grid = (B_ROWS / BM) * (OUT_F / BN);                     // 512
    lsnn_gemm<<<grid, 256, 0, stream>>>(Abf, Wbf, v, i, b, out);
}

// Round 4
// 307.498 us; speedup vs baseline: 1.1066x; 1.1066x over previous
//
#include <hip/hip_runtime.h>

#define B_ROWS 8192
#define IN_F 512
#define OUT_F 1024
#define K_TOT 1536

#define BM 64
#define BN 128
#define BK 64
#define NITER (K_TOT / BK)          // 24

#define A4_COUNT (B_ROWS * (K_TOT / 4))   // 3,145,728 float4s
#define W4_COUNT (OUT_F  * (K_TOT / 4))   //   393,216 float4s

typedef short bfrag __attribute__((ext_vector_type(8)));   // 8 bf16 = 4 VGPRs
typedef float f4    __attribute__((ext_vector_type(4)));

// round-to-nearest-even fp32 -> bf16, packed pairwise into a dword
__device__ __forceinline__ unsigned int pack2bf(float a, float b) {
    unsigned int ua = __float_as_uint(a);
    unsigned int ub = __float_as_uint(b);
    ua = (ua + 0x7fffu + ((ua >> 16) & 1u)) >> 16;
    ub = (ub + 0x7fffu + ((ub >> 16) & 1u)) & 0xffff0000u;
    return ua | ub;
}

// ---------------- pass 1: fp32 -> bf16 precast into packed A/W -------------
// A_bf16[8192][1536] = [spikes | z], W_bf16[1024][1536] = [Wi | Wr]
__global__ __launch_bounds__(256) void precast(
    const float* __restrict__ spikes, const float* __restrict__ zin,
    const float* __restrict__ Wi,     const float* __restrict__ Wr,
    unsigned short* __restrict__ Abf, unsigned short* __restrict__ Wbf)
{
    const int idx = blockIdx.x * 256 + threadIdx.x;   // float4 index
    const float* src;
    unsigned short* dst;
    if (idx < A4_COUNT) {
        const int row = idx / 384, c4 = idx - row * 384;
        src = (c4 < 128) ? spikes + (size_t)row * IN_F + c4 * 4
                         : zin    + (size_t)row * OUT_F + (c4 - 128) * 4;
        dst = Abf + (size_t)idx * 4;
    } else {
        const int w = idx - A4_COUNT;
        const int row = w / 384, c4 = w - row * 384;
        src = (c4 < 128) ? Wi + (size_t)row * IN_F + c4 * 4
                         : Wr + (size_t)row * OUT_F + (c4 - 128) * 4;
        dst = Wbf + (size_t)w * 4;
    }
    const float4 v = *(const float4*)src;
    uint2 pk = { pack2bf(v.x, v.y), pack2bf(v.z, v.w) };
    *(uint2*)dst = pk;
}

// ---------------- pass 2: bf16 GEMM + fused LSNN ---------------------------
// LDS layout: row-major 64-col rows (128 B), 16 B chunks XOR-swizzled:
// chunk col c of row r lives at slot s = c ^ (r&7). global_load_lds deposits
// at wave-base + lane*16, so lane l sources the global chunk whose swizzled
// slot is l's LDS position. ds_read then XORs back -> conflict-free-ish reads.
__global__ __launch_bounds__(256, 4) void lsnn_gemm(
    const unsigned short* __restrict__ Abf,   // [8192, 1536] bf16
    const unsigned short* __restrict__ Wbf,   // [1024, 1536] bf16
    const float* __restrict__ vin,
    const float* __restrict__ iin,
    const float* __restrict__ bin,
    float* __restrict__ out)                  // [4, B, 1024]
{
    __shared__ unsigned short As[BM * BK];    //  8 KB
    __shared__ unsigned short Ws[BN * BK];    // 16 KB

    const int tid = threadIdx.x;
    const int bid = blockIdx.x;
    const int n0 = (bid & 7) * BN;   // bid%8 = n-tile AND XCD -> W slice pinned per XCD L2
    const int m0 = (bid >> 3) * BM;

    const int lane = tid & 63;
    const int wave = tid >> 6;
    const int wm = (wave >> 1) * 32;   // 2x2 wave grid over 64x128
    const int wn = (wave & 1) * 64;
    const int lr = lane & 15;
    const int lq = lane >> 4;

    f4 acc[2][4];
    #pragma unroll
    for (int a = 0; a < 2; ++a)
        #pragma unroll
        for (int b = 0; b < 4; ++b)
            acc[a][b] = (f4)0.0f;

    const unsigned short* Ab = Abf + (size_t)m0 * K_TOT;
    const unsigned short* Wb = Wbf + (size_t)n0 * K_TOT;

    for (int it = 0; it < NITER; ++it) {
        const int kt = it * BK;
        __syncthreads();   // previous iteration's ds_reads done before overwrite

        // A: 512 chunks (64 rows x 8), 2 insts; W: 1024 chunks, 4 insts.
        #pragma unroll
        for (int p = 0; p < 2; ++p) {
            const int j0 = p * 256 + wave * 64;
            const int q  = j0 + lane;
            const int r = q >> 3, s = q & 7, c = s ^ (r & 7);
            __builtin_amdgcn_global_load_lds(
                (const __attribute__((address_space(1))) void*)(Ab + (size_t)r * K_TOT + kt + c * 8),
                (__attribute__((address_space(3))) void*)(As + j0 * 8),
                16, 0, 0);
        }
        #pragma unroll
        for (int p = 0; p < 4; ++p) {
            const int j0 = p * 256 + wave * 64;
            const int q  = j0 + lane;
            const int r = q >> 3, s = q & 7, c = s ^ (r & 7);
            __builtin_amdgcn_global_load_lds(
                (const __attribute__((address_space(1))) void*)(Wb + (size_t)r * K_TOT + kt + c * 8),
                (__attribute__((address_space(3))) void*)(Ws + j0 * 8),
                16, 0, 0);
        }
        __syncthreads();   // vmcnt drained here

        #pragma unroll
        for (int ks = 0; ks < 2; ++ks) {
            const int cc = ks * 4 + lq;        // chunk col of this lane's fragment
            bfrag af[2], wf[4];
            #pragma unroll
            for (int t = 0; t < 2; ++t) {
                const int row = wm + t * 16 + lr;
                af[t] = *(const bfrag*)&As[row * BK + (cc ^ (row & 7)) * 8];
            }
            #pragma unroll
            for (int t = 0; t < 4; ++t) {
                const int row = wn + t * 16 + lr;
                wf[t] = *(const bfrag*)&Ws[row * BK + (cc ^ (row & 7)) * 8];
            }
            #pragma unroll
            for (int tm = 0; tm < 2; ++tm)
                #pragma unroll
                for (int tn = 0; tn < 4; ++tn)
                    acc[tm][tn] = __builtin_amdgcn_mfma_f32_16x16x32_bf16(
                        af[tm], wf[tn], acc[tm][tn], 0, 0, 0);
        }
    }

    // Epilogue: C/D mapping col = lane&15, row = (lane>>4)*4 + reg (m89/m91)
    const size_t PL = (size_t)B_ROWS * OUT_F;
    #pragma unroll
    for (int tm = 0; tm < 2; ++tm) {
        #pragma unroll
        for (int tn = 0; tn < 4; ++tn) {
            #pragma unroll
            for (int r = 0; r < 4; ++r) {
                const int gm = m0 + wm + tm * 16 + lq * 4 + r;
                const int gn = n0 + wn + tn * 16 + lr;
                const size_t idx = (size_t)gm * OUT_F + gn;
                const float v = vin[idx];
                const float i = iin[idx];
                const float b = bin[idx];
                const float v_dec = v + 0.1f * ((0.0f - v) + i);   // dt*tau_mem_inv
                const float i_dec = i - 0.2f * i;                  // dt*tau_syn_inv
                const float b_dec = b + 1.25e-06f * (1.0f - b);    // dt*tau_adapt_inv
                const float zn = (v_dec - b_dec > 0.0f) ? 1.0f : 0.0f;
                const float vn = (1.0f - zn) * v_dec;              // v_reset = 0
                const float inew = i_dec + acc[tm][tn][r];
                const float bnew = b_dec + zn * 0.00225f;          // tau_adapt_inv*beta
                out[idx]          = zn;
                out[PL + idx]     = vn;
                out[2 * PL + idx] = inew;
                out[3 * PL + idx] = bnew;
            }
        }
    }
}

extern "C" void kernel_launch(void* const* d_in, const int* in_sizes, int n_in,
                              void* d_out, int out_size, void* d_ws, size_t ws_size,
                              hipStream_t stream) {
    const float* spikes = (const float*)d_in[0];
    const float* z      = (const float*)d_in[1];
    const float* v      = (const float*)d_in[2];
    const float* i      = (const float*)d_in[3];
    const float* b      = (const float*)d_in[4];
    const float* Wi     = (const float*)d_in[5];
    const float* Wr     = (const float*)d_in[6];
    float* out = (float*)d_out;

    unsigned short* Abf = (unsigned short*)d_ws;                       // 25,165,824 B
    unsigned short* Wbf = Abf + (size_t)B_ROWS * K_TOT;                //  3,145,728 B

    const int pc_grid = (A4_COUNT + W4_COUNT) / 256;                   // 13824
    precast<<<pc_grid, 256, 0, stream>>>(spikes, z, Wi, Wr, Abf, Wbf);

    const int grid = (B_ROWS / BM) * (OUT_F / BN);                     // 1024
    lsnn_gemm<<<grid, 256, 0, stream>>>(Abf, Wbf, v, i, b, out);
}

// Round 5
// 305.818 us; speedup vs baseline: 1.1127x; 1.0055x over previous
//
#include <hip/hip_runtime.h>

#define B_ROWS 8192
#define IN_F 512
#define OUT_F 1024
#define K_TOT 1536

#define BM 64
#define BN 64
#define BK 64
#define NITER (K_TOT / BK)          // 24

#define A4_COUNT (B_ROWS * (K_TOT / 4))   // 3,145,728 float4s
#define W4_COUNT (OUT_F  * (K_TOT / 4))   //   393,216 float4s

typedef short bfrag __attribute__((ext_vector_type(8)));   // 8 bf16 = 4 VGPRs
typedef float f4    __attribute__((ext_vector_type(4)));

// round-to-nearest-even fp32 -> bf16, packed pairwise into a dword
__device__ __forceinline__ unsigned int pack2bf(float a, float b) {
    unsigned int ua = __float_as_uint(a);
    unsigned int ub = __float_as_uint(b);
    ua = (ua + 0x7fffu + ((ua >> 16) & 1u)) >> 16;
    ub = (ub + 0x7fffu + ((ub >> 16) & 1u)) & 0xffff0000u;
    return ua | ub;
}

// ---------------- pass 1: fp32 -> bf16 precast into packed A/W -------------
// A_bf16[8192][1536] = [spikes | z], W_bf16[1024][1536] = [Wi | Wr]
__global__ __launch_bounds__(256) void precast(
    const float* __restrict__ spikes, const float* __restrict__ zin,
    const float* __restrict__ Wi,     const float* __restrict__ Wr,
    unsigned short* __restrict__ Abf, unsigned short* __restrict__ Wbf)
{
    const int idx = blockIdx.x * 256 + threadIdx.x;   // float4 index
    const float* src;
    unsigned short* dst;
    if (idx < A4_COUNT) {
        const int row = idx / 384, c4 = idx - row * 384;
        src = (c4 < 128) ? spikes + (size_t)row * IN_F + c4 * 4
                         : zin    + (size_t)row * OUT_F + (c4 - 128) * 4;
        dst = Abf + (size_t)idx * 4;
    } else {
        const int w = idx - A4_COUNT;
        const int row = w / 384, c4 = w - row * 384;
        src = (c4 < 128) ? Wi + (size_t)row * IN_F + c4 * 4
                         : Wr + (size_t)row * OUT_F + (c4 - 128) * 4;
        dst = Wbf + (size_t)w * 4;
    }
    const float4 v = *(const float4*)src;
    uint2 pk = { pack2bf(v.x, v.y), pack2bf(v.z, v.w) };
    *(uint2*)dst = pk;
}

// ---------------- pass 2: bf16 GEMM + fused LSNN ---------------------------
// 64x64 tile, 8 blocks/CU for latency hiding. LDS 16B chunks XOR-swizzled
// (slot s = c ^ (r&7)) -> conflict-free ds_read_b128 (verified R4: 0 conflicts).
__global__ __launch_bounds__(256, 8) void lsnn_gemm(
    const unsigned short* __restrict__ Abf,   // [8192, 1536] bf16
    const unsigned short* __restrict__ Wbf,   // [1024, 1536] bf16
    const float* __restrict__ vin,
    const float* __restrict__ iin,
    const float* __restrict__ bin,
    float* __restrict__ out)                  // [4, B, 1024]
{
    __shared__ unsigned short As[BM * BK];    // 8 KB
    __shared__ unsigned short Ws[BN * BK];    // 8 KB

    const int tid = threadIdx.x;
    const int bid = blockIdx.x;
    // bid&15 -> n-tile; XCD = bid%8 sees n-tiles {j, j+8} only -> 2 W slices
    // (2 x 192 KB) pinned per XCD L2 for the whole dispatch.
    const int n0 = (bid & 15) * BN;
    const int m0 = (bid >> 4) * BM;

    const int lane = tid & 63;
    const int wave = tid >> 6;
    const int wm = (wave >> 1) * 32;   // 2x2 wave grid over 64x64
    const int wn = (wave & 1) * 32;
    const int lr = lane & 15;
    const int lq = lane >> 4;

    f4 acc[2][2];
    #pragma unroll
    for (int a = 0; a < 2; ++a)
        #pragma unroll
        for (int b = 0; b < 2; ++b)
            acc[a][b] = (f4)0.0f;

    const unsigned short* Ab = Abf + (size_t)m0 * K_TOT;
    const unsigned short* Wb = Wbf + (size_t)n0 * K_TOT;

    for (int it = 0; it < NITER; ++it) {
        const int kt = it * BK;
        __syncthreads();   // previous iteration's ds_reads done before overwrite

        // A: 512 chunks (64 rows x 8), 2 insts; W: 512 chunks, 2 insts.
        #pragma unroll
        for (int p = 0; p < 2; ++p) {
            const int j0 = p * 256 + wave * 64;
            const int q  = j0 + lane;
            const int r = q >> 3, s = q & 7, c = s ^ (r & 7);
            __builtin_amdgcn_global_load_lds(
                (const __attribute__((address_space(1))) void*)(Ab + (size_t)r * K_TOT + kt + c * 8),
                (__attribute__((address_space(3))) void*)(As + j0 * 8),
                16, 0, 0);
        }
        #pragma unroll
        for (int p = 0; p < 2; ++p) {
            const int j0 = p * 256 + wave * 64;
            const int q  = j0 + lane;
            const int r = q >> 3, s = q & 7, c = s ^ (r & 7);
            __builtin_amdgcn_global_load_lds(
                (const __attribute__((address_space(1))) void*)(Wb + (size_t)r * K_TOT + kt + c * 8),
                (__attribute__((address_space(3))) void*)(Ws + j0 * 8),
                16, 0, 0);
        }
        __syncthreads();   // vmcnt drained here

        #pragma unroll
        for (int ks = 0; ks < 2; ++ks) {
            const int cc = ks * 4 + lq;        // chunk col of this lane's fragment
            bfrag af[2], wf[2];
            #pragma unroll
            for (int t = 0; t < 2; ++t) {
                const int row = wm + t * 16 + lr;
                af[t] = *(const bfrag*)&As[row * BK + (cc ^ (row & 7)) * 8];
            }
            #pragma unroll
            for (int t = 0; t < 2; ++t) {
                const int row = wn + t * 16 + lr;
                wf[t] = *(const bfrag*)&Ws[row * BK + (cc ^ (row & 7)) * 8];
            }
            #pragma unroll
            for (int tm = 0; tm < 2; ++tm)
                #pragma unroll
                for (int tn = 0; tn < 2; ++tn)
                    acc[tm][tn] = __builtin_amdgcn_mfma_f32_16x16x32_bf16(
                        af[tm], wf[tn], acc[tm][tn], 0, 0, 0);
        }
    }

    // Epilogue: C/D mapping col = lane&15, row = (lane>>4)*4 + reg (m89/m91)
    const size_t PL = (size_t)B_ROWS * OUT_F;
    #pragma unroll
    for (int tm = 0; tm < 2; ++tm) {
        #pragma unroll
        for (int tn = 0; tn < 2; ++tn) {
            #pragma unroll
            for (int r = 0; r < 4; ++r) {
                const int gm = m0 + wm + tm * 16 + lq * 4 + r;
                const int gn = n0 + wn + tn * 16 + lr;
                const size_t idx = (size_t)gm * OUT_F + gn;
                const float v = vin[idx];
                const float i = iin[idx];
                const float b = bin[idx];
                const float v_dec = v + 0.1f * ((0.0f - v) + i);   // dt*tau_mem_inv
                const float i_dec = i - 0.2f * i;                  // dt*tau_syn_inv
                const float b_dec = b + 1.25e-06f * (1.0f - b);    // dt*tau_adapt_inv
                const float zn = (v_dec - b_dec > 0.0f) ? 1.0f : 0.0f;
                const float vn = (1.0f - zn) * v_dec;              // v_reset = 0
                const float inew = i_dec + acc[tm][tn][r];
                const float bnew = b_dec + zn * 0.00225f;          // tau_adapt_inv*beta
                out[idx]          = zn;
                out[PL + idx]     = vn;
                out[2 * PL + idx] = inew;
                out[3 * PL + idx] = bnew;
            }
        }
    }
}

extern "C" void kernel_launch(void* const* d_in, const int* in_sizes, int n_in,
                              void* d_out, int out_size, void* d_ws, size_t ws_size,
                              hipStream_t stream) {
    const float* spikes = (const float*)d_in[0];
    const float* z      = (const float*)d_in[1];
    const float* v      = (const float*)d_in[2];
    const float* i      = (const float*)d_in[3];
    const float* b      = (const float*)d_in[4];
    const float* Wi     = (const float*)d_in[5];
    const float* Wr     = (const float*)d_in[6];
    float* out = (float*)d_out;

    unsigned short* Abf = (unsigned short*)d_ws;                       // 25,165,824 B
    unsigned short* Wbf = Abf + (size_t)B_ROWS * K_TOT;                //  3,145,728 B

    const int pc_grid = (A4_COUNT + W4_COUNT) / 256;                   // 13824
    precast<<<pc_grid, 256, 0, stream>>>(spikes, z, Wi, Wr, Abf, Wbf);

    const int grid = (B_ROWS / BM) * (OUT_F / BN);                     // 2048
    lsnn_gemm<<<grid, 256, 0, stream>>>(Abf, Wbf, v, i, b, out);
}